// Round 1
// baseline (170.572 us; speedup 1.0000x reference)
//
#include <hip/hip_runtime.h>

#define NB 32
#define NT 512
#define ND 80
#define NK 16
#define NP 64

// D*log(2*pi)
#define C_DLOG2PI (80.0f * 1.837877066409345f)

__global__ void zero_out_kernel(float* out) { out[0] = 0.0f; }

// One block per (b,k). 512 threads, one t per thread.
// Stage L (80x80 fp32 = 25.6KB) + mu in LDS; per-thread fully-unrolled
// forward substitution with LDS-broadcast reads of L.
__global__ __launch_bounds__(512) void nll_kernel(
    const float* __restrict__ x,
    const float* __restrict__ mu_subj,
    const float* __restrict__ L_subj,
    const float* __restrict__ gamma,
    const int* __restrict__ sids,
    float* __restrict__ out)
{
    const int bk  = blockIdx.x;
    const int b   = bk / NK;
    const int k   = bk % NK;
    const int tid = threadIdx.x;
    const int s   = sids[b];

    __shared__ float Ls[ND * ND];
    __shared__ float mus[ND];
    __shared__ float invd[ND];
    __shared__ float logd[ND];
    __shared__ float logdet_sh;
    __shared__ float partial[8];

    const float* Lg = L_subj + (((size_t)s * NK + k) * ND * ND);
    for (int i = tid; i < ND * ND; i += 512) Ls[i] = Lg[i];
    const float* mg = mu_subj + (((size_t)s * NK + k) * ND);
    if (tid < ND) mus[tid] = mg[tid];
    __syncthreads();

    if (tid < ND) {
        float dg = Ls[tid * ND + tid];
        invd[tid] = 1.0f / dg;
        logd[tid] = logf(dg);
    }
    __syncthreads();
    if (tid == 0) {
        float sum = 0.0f;
        for (int i = 0; i < ND; ++i) sum += logd[i];
        logdet_sh = 2.0f * sum;
    }
    __syncthreads();
    const float logdet = logdet_sh;

    // r computed up front; y overwrites r in place (r[i] dead once row i runs).
    const int t = tid;  // NT == 512 == blockDim.x
    const float* xp = x + (((size_t)b * NT + t) * ND);
    float r[ND];
    #pragma unroll
    for (int i4 = 0; i4 < ND / 4; ++i4) {
        float4 v = reinterpret_cast<const float4*>(xp)[i4];
        r[4 * i4 + 0] = v.x - mus[4 * i4 + 0];
        r[4 * i4 + 1] = v.y - mus[4 * i4 + 1];
        r[4 * i4 + 2] = v.z - mus[4 * i4 + 2];
        r[4 * i4 + 3] = v.w - mus[4 * i4 + 3];
    }

    float mahal = 0.0f;
    #pragma unroll
    for (int i = 0; i < ND; ++i) {
        float acc = r[i];
        #pragma unroll
        for (int j = 0; j < i; ++j) acc -= Ls[i * ND + j] * r[j];
        float yi = acc * invd[i];
        r[i] = yi;
        mahal += yi * yi;
    }

    float logp = -0.5f * (C_DLOG2PI + logdet + mahal);
    float g = gamma[(((size_t)b * NT + t) * NK) + k];
    float local = g * logp;

    // wave (64-lane) reduce, then cross-wave via LDS
    #pragma unroll
    for (int off = 32; off > 0; off >>= 1) local += __shfl_down(local, off);
    int wave = tid >> 6;
    if ((tid & 63) == 0) partial[wave] = local;
    __syncthreads();
    if (tid == 0) {
        float sum = 0.0f;
        #pragma unroll
        for (int w = 0; w < 8; ++w) sum += partial[w];
        atomicAdd(out, -sum * (1.0f / (NB * NT)));
    }
}

// One block per subject p. Computes mask/S from subject_ids, then the
// masked Frobenius penalties.
__global__ __launch_bounds__(256) void reg_kernel(
    const float* __restrict__ mu_pop,
    const float* __restrict__ L_pop,
    const float* __restrict__ mu_subj,
    const float* __restrict__ L_subj,
    const int* __restrict__ sids,
    float* __restrict__ out)
{
    const int p   = blockIdx.x;
    const int tid = threadIdx.x;

    __shared__ int maskS[NP];
    __shared__ int S_sh;
    __shared__ float partial[4];

    if (tid < NP) {
        int f = 0;
        for (int b = 0; b < NB; ++b) f |= (sids[b] == tid) ? 1 : 0;
        maskS[tid] = f;
    }
    __syncthreads();
    if (tid == 0) {
        int scount = 0;
        for (int q = 0; q < NP; ++q) scount += maskS[q];
        S_sh = scount;
    }
    __syncthreads();

    if (!maskS[p]) return;  // uniform exit

    float acc = 0.0f;
    const float* ms = mu_subj + (size_t)p * NK * ND;
    for (int i = tid; i < NK * ND; i += 256) {
        float d = ms[i] - mu_pop[i];
        acc += d * d;
    }
    const float* Lsu = L_subj + (size_t)p * NK * ND * ND;
    for (int i = tid; i < NK * ND * ND; i += 256) {
        float d = Lsu[i] - L_pop[i];
        acc += d * d;
    }

    #pragma unroll
    for (int off = 32; off > 0; off >>= 1) acc += __shfl_down(acc, off);
    int wave = tid >> 6;
    if ((tid & 63) == 0) partial[wave] = acc;
    __syncthreads();
    if (tid == 0) {
        float total = partial[0] + partial[1] + partial[2] + partial[3];
        float scale = (float)S_sh / (float)NP;
        // LAMBDA_MU/2 == LAMBDA_L/2 == 0.05 for both terms
        atomicAdd(out, scale * 0.05f * total);
    }
}

extern "C" void kernel_launch(void* const* d_in, const int* in_sizes, int n_in,
                              void* d_out, int out_size, void* d_ws, size_t ws_size,
                              hipStream_t stream) {
    (void)in_sizes; (void)n_in; (void)d_ws; (void)ws_size; (void)out_size;
    const float* x       = (const float*)d_in[0];
    const float* mu_pop  = (const float*)d_in[1];
    const float* L_pop   = (const float*)d_in[2];
    const float* mu_subj = (const float*)d_in[3];
    const float* L_subj  = (const float*)d_in[4];
    const float* gamma   = (const float*)d_in[5];
    const int*   sids    = (const int*)d_in[6];
    float* out = (float*)d_out;

    hipLaunchKernelGGL(zero_out_kernel, dim3(1), dim3(1), 0, stream, out);
    hipLaunchKernelGGL(nll_kernel, dim3(NB * NK), dim3(512), 0, stream,
                       x, mu_subj, L_subj, gamma, sids, out);
    hipLaunchKernelGGL(reg_kernel, dim3(NP), dim3(256), 0, stream,
                       mu_pop, L_pop, mu_subj, L_subj, sids, out);
}

// Round 2
// 69.983 us; speedup vs baseline: 2.4373x; 2.4373x over previous
//
#include <hip/hip_runtime.h>

#define NB 32
#define NT 512
#define ND 80
#define NK 16
#define NP 64

// D*log(2*pi)
#define C_DLOG2PI (80.0f * 1.837877066409345f)

#define REG_CHUNKS 16

__global__ void zero_out_kernel(float* out) { out[0] = 0.0f; }

// One block per (b,k). 512 threads, one t per thread.
// Stage L (80x80 fp32 = 25.6KB) + mu in LDS; per-thread fully-unrolled
// forward substitution with LDS-broadcast reads of L.
__global__ __launch_bounds__(512) void nll_kernel(
    const float* __restrict__ x,
    const float* __restrict__ mu_subj,
    const float* __restrict__ L_subj,
    const float* __restrict__ gamma,
    const int* __restrict__ sids,
    float* __restrict__ out)
{
    const int bk  = blockIdx.x;
    const int b   = bk / NK;
    const int k   = bk % NK;
    const int tid = threadIdx.x;
    const int s   = sids[b];

    __shared__ float Ls[ND * ND];
    __shared__ float mus[ND];
    __shared__ float invd[ND];
    __shared__ float logd[ND];
    __shared__ float logdet_sh;
    __shared__ float partial[8];

    const float* Lg = L_subj + (((size_t)s * NK + k) * ND * ND);
    for (int i = tid; i < ND * ND; i += 512) Ls[i] = Lg[i];
    const float* mg = mu_subj + (((size_t)s * NK + k) * ND);
    if (tid < ND) mus[tid] = mg[tid];
    __syncthreads();

    if (tid < ND) {
        float dg = Ls[tid * ND + tid];
        invd[tid] = 1.0f / dg;
        logd[tid] = logf(dg);
    }
    __syncthreads();
    if (tid == 0) {
        float sum = 0.0f;
        for (int i = 0; i < ND; ++i) sum += logd[i];
        logdet_sh = 2.0f * sum;
    }
    __syncthreads();
    const float logdet = logdet_sh;

    // r computed up front; y overwrites r in place (r[i] dead once row i runs).
    const int t = tid;  // NT == 512 == blockDim.x
    const float* xp = x + (((size_t)b * NT + t) * ND);
    float r[ND];
    #pragma unroll
    for (int i4 = 0; i4 < ND / 4; ++i4) {
        float4 v = reinterpret_cast<const float4*>(xp)[i4];
        r[4 * i4 + 0] = v.x - mus[4 * i4 + 0];
        r[4 * i4 + 1] = v.y - mus[4 * i4 + 1];
        r[4 * i4 + 2] = v.z - mus[4 * i4 + 2];
        r[4 * i4 + 3] = v.w - mus[4 * i4 + 3];
    }

    float mahal = 0.0f;
    #pragma unroll
    for (int i = 0; i < ND; ++i) {
        float acc = r[i];
        #pragma unroll
        for (int j = 0; j < i; ++j) acc -= Ls[i * ND + j] * r[j];
        float yi = acc * invd[i];
        r[i] = yi;
        mahal += yi * yi;
    }

    float logp = -0.5f * (C_DLOG2PI + logdet + mahal);
    float g = gamma[(((size_t)b * NT + t) * NK) + k];
    float local = g * logp;

    // wave (64-lane) reduce, then cross-wave via LDS
    #pragma unroll
    for (int off = 32; off > 0; off >>= 1) local += __shfl_down(local, off);
    int wave = tid >> 6;
    if ((tid & 63) == 0) partial[wave] = local;
    __syncthreads();
    if (tid == 0) {
        float sum = 0.0f;
        #pragma unroll
        for (int w = 0; w < 8; ++w) sum += partial[w];
        atomicAdd(out, -sum * (1.0f / (NB * NT)));
    }
}

// Grid (REG_CHUNKS, NP). Block (chunk c, subject p) handles a float4-strided
// slice of the (K,D,D) L-penalty for subject p; chunk 0 also does the
// (K,D) mu-penalty. Absent subjects exit uniformly after the mask check.
__global__ __launch_bounds__(256) void reg_kernel(
    const float* __restrict__ mu_pop,
    const float* __restrict__ L_pop,
    const float* __restrict__ mu_subj,
    const float* __restrict__ L_subj,
    const int* __restrict__ sids,
    float* __restrict__ out)
{
    const int p   = blockIdx.y;
    const int c   = blockIdx.x;
    const int tid = threadIdx.x;

    __shared__ float scale_sh;
    __shared__ int   present_sh;
    __shared__ float partial[4];

    if (tid == 0) {
        unsigned long long seen = 0ull;
        int present = 0;
        for (int b = 0; b < NB; ++b) {
            int sb = sids[b];
            seen |= (1ull << sb);
            present |= (sb == p) ? 1 : 0;
        }
        present_sh = present;
        scale_sh = (float)__popcll(seen) * (1.0f / (float)NP);
    }
    __syncthreads();
    if (!present_sh) return;  // uniform exit

    float acc = 0.0f;

    // L penalty: NK*ND*ND = 102400 floats = 25600 float4 per subject.
    {
        const float4* Ls4 = reinterpret_cast<const float4*>(L_subj + (size_t)p * NK * ND * ND);
        const float4* Lp4 = reinterpret_cast<const float4*>(L_pop);
        const int n4 = NK * ND * ND / 4;
        for (int i = c * 256 + tid; i < n4; i += REG_CHUNKS * 256) {
            float4 a = Ls4[i];
            float4 bq = Lp4[i];
            float dx = a.x - bq.x, dy = a.y - bq.y, dz = a.z - bq.z, dw = a.w - bq.w;
            acc += dx * dx + dy * dy + dz * dz + dw * dw;
        }
    }
    // mu penalty: NK*ND = 1280 floats = 320 float4, chunk 0 only.
    if (c == 0) {
        const float4* ms4 = reinterpret_cast<const float4*>(mu_subj + (size_t)p * NK * ND);
        const float4* mp4 = reinterpret_cast<const float4*>(mu_pop);
        const int n4 = NK * ND / 4;
        for (int i = tid; i < n4; i += 256) {
            float4 a = ms4[i];
            float4 bq = mp4[i];
            float dx = a.x - bq.x, dy = a.y - bq.y, dz = a.z - bq.z, dw = a.w - bq.w;
            acc += dx * dx + dy * dy + dz * dz + dw * dw;
        }
    }

    #pragma unroll
    for (int off = 32; off > 0; off >>= 1) acc += __shfl_down(acc, off);
    int wave = tid >> 6;
    if ((tid & 63) == 0) partial[wave] = acc;
    __syncthreads();
    if (tid == 0) {
        float total = partial[0] + partial[1] + partial[2] + partial[3];
        // LAMBDA_MU/2 == LAMBDA_L/2 == 0.05 for both terms
        atomicAdd(out, scale_sh * 0.05f * total);
    }
}

extern "C" void kernel_launch(void* const* d_in, const int* in_sizes, int n_in,
                              void* d_out, int out_size, void* d_ws, size_t ws_size,
                              hipStream_t stream) {
    (void)in_sizes; (void)n_in; (void)d_ws; (void)ws_size; (void)out_size;
    const float* x       = (const float*)d_in[0];
    const float* mu_pop  = (const float*)d_in[1];
    const float* L_pop   = (const float*)d_in[2];
    const float* mu_subj = (const float*)d_in[3];
    const float* L_subj  = (const float*)d_in[4];
    const float* gamma   = (const float*)d_in[5];
    const int*   sids    = (const int*)d_in[6];
    float* out = (float*)d_out;

    hipLaunchKernelGGL(zero_out_kernel, dim3(1), dim3(1), 0, stream, out);
    hipLaunchKernelGGL(nll_kernel, dim3(NB * NK), dim3(512), 0, stream,
                       x, mu_subj, L_subj, gamma, sids, out);
    hipLaunchKernelGGL(reg_kernel, dim3(REG_CHUNKS, NP), dim3(256), 0, stream,
                       mu_pop, L_pop, mu_subj, L_subj, sids, out);
}